// Round 8
// baseline (108.925 us; speedup 1.0000x reference)
//
#include <hip/hip_runtime.h>

// Problem constants (fixed by setup_inputs): B=8, H=W=512, D=32, K=64
#define B_    8
#define N_    (512 * 512)
#define D_    32
#define K_    64
#define TPB   256
#define NWAVE (TPB / 64)
#define KROW  36                 // row stride (floats): 16B-aligned, spreads banks
#define TABW  (K_ * KROW)        // 2304 floats per wave-private table
#define REC   (K_ * D_ + K_)     // per-block partial record: 2048 sums + 64 counts
#define RECQ  (REC / 4)          // 528 float4 quads per record

// ---------------------------------------------------------------------------
// Stage 1: per-block partial segment sums. Straight-line duplicate handling
// + 2-deep software pipeline via macro-expanded NAMED registers (proven r6;
// r7 showed 4-deep is neutral -> keep the lower-VGPR 2-deep form).
// order==0 lane does the plain float4 RMW and adds the whole group's count;
// order>0 lanes (~4%) issue ds_add atomics AFTER the write in program order
// (same-wave LDS ops complete in issue order -> race-free).
// ---------------------------------------------------------------------------

// Process one iteration's registers, refilling them from PBASE (2 iters ahead).
#define PROC(L0,L1,L2,L3,L4,L5,L6,L7, V, PBASE)                               \
  {                                                                           \
    int lb = egl < 4 ? (egl < 2 ? (egl == 0 ? L0 : L1)                        \
                                : (egl == 2 ? L2 : L3))                       \
                     : (egl < 6 ? (egl == 4 ? L4 : L5)                        \
                                : (egl == 6 ? L6 : L7));                      \
    const int m0 = (lb == L0), m1 = (lb == L1), m2 = (lb == L2),              \
              m3 = (lb == L3), m4 = (lb == L4), m5 = (lb == L5),              \
              m6 = (lb == L6), m7 = (lb == L7);                               \
    const int order = (g0 & m0) + (g1 & m1) + (g2 & m2) + (g3 & m3) +         \
                      (g4 & m4) + (g5 & m5) + (g6 & m6);                      \
    const int nsame = m0 + m1 + m2 + m3 + m4 + m5 + m6 + m7;                  \
    const float4 vc = V;                                                      \
    const int pb = (PBASE);                                                   \
    if (pb < N_) {        /* uniform branch */                                \
      const int* lp = lab + bbase + pb + wb;   /* wave-uniform -> s_load */   \
      L0 = lp[0]; L1 = lp[1]; L2 = lp[2]; L3 = lp[3];                         \
      L4 = lp[4]; L5 = lp[5]; L6 = lp[6]; L7 = lp[7];                         \
      V = embv[(bbase + pb + eg) * 8 + d4];                                   \
    }                                                                         \
    const int a = lb * KROW + d4 * 4;                                         \
    if (order == 0) {                                                         \
      float4 cur = *reinterpret_cast<const float4*>(tab + a);                 \
      cur.x += vc.x; cur.y += vc.y; cur.z += vc.z; cur.w += vc.w;             \
      *reinterpret_cast<float4*>(tab + a) = cur;                              \
      if (d4 == 0) cnt[lb] += (float)nsame;                                   \
    } else {  /* rare; lands after the write in issue order */                \
      atomicAdd(&tab[a + 0], vc.x);                                           \
      atomicAdd(&tab[a + 1], vc.y);                                           \
      atomicAdd(&tab[a + 2], vc.z);                                           \
      atomicAdd(&tab[a + 3], vc.w);                                           \
    }                                                                         \
  }

__global__ __launch_bounds__(TPB) void seg_partial_kernel(
    const float* __restrict__ emb, const int* __restrict__ lab,
    float* __restrict__ partials, int blk_per_b)
{
    __shared__ __align__(16) float s_tab[NWAVE * TABW];
    __shared__ float s_cnt[NWAVE * K_];

    for (int i = threadIdx.x; i < NWAVE * TABW; i += TPB) s_tab[i] = 0.f;
    for (int i = threadIdx.x; i < NWAVE * K_;  i += TPB) s_cnt[i] = 0.f;
    __syncthreads();

    const int tid  = threadIdx.x;
    const int wave = tid >> 6;
    const int lane = tid & 63;
    const int egl  = lane >> 3;          // element slot within wave: 0..7
    const int d4   = lane & 7;           // float4 slice within element: 0..7
    const int eg   = wave * 8 + egl;     // element slot within block-iter: 0..31

    // loop-invariant "slot i is earlier than mine" predicates
    const int g0 = (0 < egl), g1 = (1 < egl), g2 = (2 < egl), g3 = (3 < egl),
              g4 = (4 < egl), g5 = (5 < egl), g6 = (6 < egl);

    float* __restrict__ tab = s_tab + wave * TABW;
    float* __restrict__ cnt = s_cnt + wave * K_;

    const int blk = blockIdx.x;
    const int b   = blk / blk_per_b;
    const int bib = blk - b * blk_per_b;
    const long long bbase = (long long)b * N_;
    const float4* __restrict__ embv = reinterpret_cast<const float4*>(emb);
    const int STEP = blk_per_b * 32;
    const int wb = __builtin_amdgcn_readfirstlane(wave * 8);

    int ib = bib * 32;

    // prologue: fill both pipeline stages (A @ ib, B @ ib+STEP)
    int a0, a1, a2, a3, a4, a5, a6, a7;
    float4 va;
    {
        const int* lp = lab + bbase + ib + wb;
        a0 = lp[0]; a1 = lp[1]; a2 = lp[2]; a3 = lp[3];
        a4 = lp[4]; a5 = lp[5]; a6 = lp[6]; a7 = lp[7];
        va = embv[(bbase + ib + eg) * 8 + d4];
    }
    int b0 = 0, b1 = 0, b2 = 0, b3 = 0, b4 = 0, b5 = 0, b6 = 0, b7 = 0;
    float4 vb = make_float4(0.f, 0.f, 0.f, 0.f);
    if (ib + STEP < N_) {
        const int* lp = lab + bbase + ib + STEP + wb;
        b0 = lp[0]; b1 = lp[1]; b2 = lp[2]; b3 = lp[3];
        b4 = lp[4]; b5 = lp[5]; b6 = lp[6]; b7 = lp[7];
        vb = embv[(bbase + ib + STEP + eg) * 8 + d4];
    }

    for (;;) {
        PROC(a0, a1, a2, a3, a4, a5, a6, a7, va, ib + 2 * STEP);
        ib += STEP;
        if (ib >= N_) break;
        PROC(b0, b1, b2, b3, b4, b5, b6, b7, vb, ib + 2 * STEP);
        ib += STEP;
        if (ib >= N_) break;
    }
    __syncthreads();

    // merge the 4 wave tables, write one partial record per block
    float* out = partials + (size_t)blk * REC;
    for (int i = tid; i < K_ * D_; i += TPB) {
        int k = i >> 5, d = i & 31;
        float s = 0.f;
#pragma unroll
        for (int w = 0; w < NWAVE; ++w) s += s_tab[w * TABW + k * KROW + d];
        out[i] = s;
    }
    if (tid < K_) {
        float c = 0.f;
#pragma unroll
        for (int w = 0; w < NWAVE; ++w) c += s_cnt[w * K_ + tid];
        out[K_ * D_ + tid] = c;
    }
}

// ---------------------------------------------------------------------------
// Stage 2+3 FUSED: one block per batch.
// Phase A: thread t OWNS record-quads {t, t+256, (t<16: 512+t)} in registers
// (named accs — no runtime indexing, no scratch) and sweeps all 128 records;
// loads are coalesced (256 consecutive float4 = 4 KB per step), unroll 8.
// Phase B: scatter to transposed s_cent4[j][k], normalize, pair-loss, write
// batch_loss[b]. Quad q<512 maps to (k = q>>3, j = q&7); quads 512..527 are
// the 64 counts.
// ---------------------------------------------------------------------------
__global__ __launch_bounds__(TPB) void reduce_loss_kernel(
    const float* __restrict__ partials, float* __restrict__ batch_loss,
    int blk_per_b)
{
    __shared__ __align__(16) float4 s_cent4[8 * K_];  // [j][k]
    __shared__ float s_cntsh[K_];
    __shared__ float s_pres[K_];
    __shared__ float s_wred[NWAVE];

    const int b   = blockIdx.x;
    const int tid = threadIdx.x;
    const float4* __restrict__ p4 =
        reinterpret_cast<const float4*>(partials + (size_t)b * blk_per_b * REC);

    float4 acc0 = make_float4(0.f, 0.f, 0.f, 0.f);
    float4 acc1 = acc0, acc2 = acc0;
#pragma unroll 8
    for (int r = 0; r < blk_per_b; ++r) {
        const float4* rp = p4 + (size_t)r * RECQ;
        float4 v0 = rp[tid];
        float4 v1 = rp[tid + 256];
        acc0.x += v0.x; acc0.y += v0.y; acc0.z += v0.z; acc0.w += v0.w;
        acc1.x += v1.x; acc1.y += v1.y; acc1.z += v1.z; acc1.w += v1.w;
        if (tid < 16) {
            float4 v2 = rp[tid + 512];
            acc2.x += v2.x; acc2.y += v2.y; acc2.z += v2.z; acc2.w += v2.w;
        }
    }

    // scatter: quad q -> s_cent4[(q&7)*64 + (q>>3)]
    s_cent4[(tid & 7) * K_ + (tid >> 3)] = acc0;
    {
        const int q1 = tid + 256;
        s_cent4[(q1 & 7) * K_ + (q1 >> 3)] = acc1;
    }
    if (tid < 16) reinterpret_cast<float4*>(s_cntsh)[tid] = acc2;
    __syncthreads();

    if (tid < K_) s_pres[tid] = (s_cntsh[tid] > 0.5f) ? 1.f : 0.f;
    for (int i = tid; i < 8 * K_; i += TPB) {
        float inv = 1.0f / fmaxf(s_cntsh[i & 63], 1.0f);
        float4 c = s_cent4[i];
        c.x *= inv; c.y *= inv; c.z *= inv; c.w *= inv;
        s_cent4[i] = c;
    }
    __syncthreads();

    const int wave = tid >> 6, lane = tid & 63;

    float4 cb[8];
#pragma unroll
    for (int j = 0; j < 8; ++j) cb[j] = s_cent4[j * K_ + lane];
    const float pres2 = s_pres[lane];

    float acc = 0.f;
#pragma unroll 4
    for (int t = 0; t < 16; ++t) {
        const int k1 = wave * 16 + t;
        float dist = 0.f;
#pragma unroll
        for (int j = 0; j < 8; ++j) {
            float4 a = s_cent4[j * K_ + k1];   // wave-uniform broadcast
            dist += fabsf(a.x - cb[j].x) + fabsf(a.y - cb[j].y)
                  + fabsf(a.z - cb[j].z) + fabsf(a.w - cb[j].w);
        }
        float h = fmaxf(0.25f - dist, 0.f);
        float valid = (k1 < lane) ? s_pres[k1] * pres2 : 0.f;
        acc += valid * h * h;
    }
#pragma unroll
    for (int m = 32; m > 0; m >>= 1) acc += __shfl_xor(acc, m);
    if (lane == 0) s_wred[wave] = acc;
    __syncthreads();
    if (tid == 0) {
        float s = s_wred[0] + s_wred[1] + s_wred[2] + s_wred[3];
        float n = 0.f;
        for (int k = 0; k < K_; ++k) n += s_pres[k];
        float ncomp = n * (n - 1.f) * 0.5f;
        batch_loss[b] = (ncomp > 0.f) ? (s / ncomp) : 0.f;
    }
}

// ---------------------------------------------------------------------------
// Stage 4: average the 8 per-batch losses into out[0].
// ---------------------------------------------------------------------------
__global__ void final_kernel(const float* __restrict__ batch_loss,
                             float* __restrict__ out)
{
    if (threadIdx.x == 0) {
        float t = 0.f;
#pragma unroll
        for (int b = 0; b < B_; ++b) t += batch_loss[b];
        out[0] = t * (1.0f / (float)B_);
    }
}

// ---------------------------------------------------------------------------
extern "C" void kernel_launch(void* const* d_in, const int* in_sizes, int n_in,
                              void* d_out, int out_size, void* d_ws, size_t ws_size,
                              hipStream_t stream)
{
    const float* emb = (const float*)d_in[0];
    const int*   lab = (const int*)d_in[1];
    float*       out = (float*)d_out;
    float*       ws  = (float*)d_ws;

    int blk_per_b = 128;
    const size_t tail_floats = (size_t)B_;
    while (blk_per_b > 1) {
        size_t need = ((size_t)(blk_per_b * B_) * REC + tail_floats) * sizeof(float);
        if (need <= ws_size) break;
        blk_per_b >>= 1;
    }
    const int nblk = blk_per_b * B_;

    float* partials   = ws;
    float* batch_loss = ws + (size_t)nblk * REC;

    seg_partial_kernel<<<nblk, TPB, 0, stream>>>(emb, lab, partials, blk_per_b);

    reduce_loss_kernel<<<B_, TPB, 0, stream>>>(partials, batch_loss, blk_per_b);

    final_kernel<<<1, 64, 0, stream>>>(batch_loss, out);
}

// Round 9
// 74.715 us; speedup vs baseline: 1.4579x; 1.4579x over previous
//
#include <hip/hip_runtime.h>

// Problem constants (fixed by setup_inputs): B=8, H=W=512, D=32, K=64
#define B_    8
#define N_    (512 * 512)
#define D_    32
#define K_    64
#define TPB   256
#define NWAVE (TPB / 64)
#define KROW  36                 // row stride (floats): 16B-aligned, spreads banks
#define TABW  (K_ * KROW)        // 2304 floats per wave-private table
#define REC   (K_ * D_ + K_)     // per-block partial record: 2048 sums + 64 counts
#define RECQ  (REC / 4)          // 528 float4 quads per record

// ---------------------------------------------------------------------------
// Stage 1: per-block partial segment sums (UNCHANGED from r6 — proven 2-deep
// pipeline; r7 showed 4-deep neutral because stage1 sits at the HBM BW floor).
// ---------------------------------------------------------------------------
#define PROC(L0,L1,L2,L3,L4,L5,L6,L7, V, PBASE)                               \
  {                                                                           \
    int lb = egl < 4 ? (egl < 2 ? (egl == 0 ? L0 : L1)                        \
                                : (egl == 2 ? L2 : L3))                       \
                     : (egl < 6 ? (egl == 4 ? L4 : L5)                        \
                                : (egl == 6 ? L6 : L7));                      \
    const int m0 = (lb == L0), m1 = (lb == L1), m2 = (lb == L2),              \
              m3 = (lb == L3), m4 = (lb == L4), m5 = (lb == L5),              \
              m6 = (lb == L6), m7 = (lb == L7);                               \
    const int order = (g0 & m0) + (g1 & m1) + (g2 & m2) + (g3 & m3) +         \
                      (g4 & m4) + (g5 & m5) + (g6 & m6);                      \
    const int nsame = m0 + m1 + m2 + m3 + m4 + m5 + m6 + m7;                  \
    const float4 vc = V;                                                      \
    const int pb = (PBASE);                                                   \
    if (pb < N_) {        /* uniform branch */                                \
      const int* lp = lab + bbase + pb + wb;   /* wave-uniform -> s_load */   \
      L0 = lp[0]; L1 = lp[1]; L2 = lp[2]; L3 = lp[3];                         \
      L4 = lp[4]; L5 = lp[5]; L6 = lp[6]; L7 = lp[7];                         \
      V = embv[(bbase + pb + eg) * 8 + d4];                                   \
    }                                                                         \
    const int a = lb * KROW + d4 * 4;                                         \
    if (order == 0) {                                                         \
      float4 cur = *reinterpret_cast<const float4*>(tab + a);                 \
      cur.x += vc.x; cur.y += vc.y; cur.z += vc.z; cur.w += vc.w;             \
      *reinterpret_cast<float4*>(tab + a) = cur;                              \
      if (d4 == 0) cnt[lb] += (float)nsame;                                   \
    } else {  /* rare; lands after the write in issue order */                \
      atomicAdd(&tab[a + 0], vc.x);                                           \
      atomicAdd(&tab[a + 1], vc.y);                                           \
      atomicAdd(&tab[a + 2], vc.z);                                           \
      atomicAdd(&tab[a + 3], vc.w);                                           \
    }                                                                         \
  }

__global__ __launch_bounds__(TPB) void seg_partial_kernel(
    const float* __restrict__ emb, const int* __restrict__ lab,
    float* __restrict__ partials, int blk_per_b)
{
    __shared__ __align__(16) float s_tab[NWAVE * TABW];
    __shared__ float s_cnt[NWAVE * K_];

    for (int i = threadIdx.x; i < NWAVE * TABW; i += TPB) s_tab[i] = 0.f;
    for (int i = threadIdx.x; i < NWAVE * K_;  i += TPB) s_cnt[i] = 0.f;
    __syncthreads();

    const int tid  = threadIdx.x;
    const int wave = tid >> 6;
    const int lane = tid & 63;
    const int egl  = lane >> 3;          // element slot within wave: 0..7
    const int d4   = lane & 7;           // float4 slice within element: 0..7
    const int eg   = wave * 8 + egl;     // element slot within block-iter: 0..31

    const int g0 = (0 < egl), g1 = (1 < egl), g2 = (2 < egl), g3 = (3 < egl),
              g4 = (4 < egl), g5 = (5 < egl), g6 = (6 < egl);

    float* __restrict__ tab = s_tab + wave * TABW;
    float* __restrict__ cnt = s_cnt + wave * K_;

    const int blk = blockIdx.x;
    const int b   = blk / blk_per_b;
    const int bib = blk - b * blk_per_b;
    const long long bbase = (long long)b * N_;
    const float4* __restrict__ embv = reinterpret_cast<const float4*>(emb);
    const int STEP = blk_per_b * 32;
    const int wb = __builtin_amdgcn_readfirstlane(wave * 8);

    int ib = bib * 32;

    int a0, a1, a2, a3, a4, a5, a6, a7;
    float4 va;
    {
        const int* lp = lab + bbase + ib + wb;
        a0 = lp[0]; a1 = lp[1]; a2 = lp[2]; a3 = lp[3];
        a4 = lp[4]; a5 = lp[5]; a6 = lp[6]; a7 = lp[7];
        va = embv[(bbase + ib + eg) * 8 + d4];
    }
    int b0 = 0, b1 = 0, b2 = 0, b3 = 0, b4 = 0, b5 = 0, b6 = 0, b7 = 0;
    float4 vb = make_float4(0.f, 0.f, 0.f, 0.f);
    if (ib + STEP < N_) {
        const int* lp = lab + bbase + ib + STEP + wb;
        b0 = lp[0]; b1 = lp[1]; b2 = lp[2]; b3 = lp[3];
        b4 = lp[4]; b5 = lp[5]; b6 = lp[6]; b7 = lp[7];
        vb = embv[(bbase + ib + STEP + eg) * 8 + d4];
    }

    for (;;) {
        PROC(a0, a1, a2, a3, a4, a5, a6, a7, va, ib + 2 * STEP);
        ib += STEP;
        if (ib >= N_) break;
        PROC(b0, b1, b2, b3, b4, b5, b6, b7, vb, ib + 2 * STEP);
        ib += STEP;
        if (ib >= N_) break;
    }
    __syncthreads();

    float* out = partials + (size_t)blk * REC;
    for (int i = tid; i < K_ * D_; i += TPB) {
        int k = i >> 5, d = i & 31;
        float s = 0.f;
#pragma unroll
        for (int w = 0; w < NWAVE; ++w) s += s_tab[w * TABW + k * KROW + d];
        out[i] = s;
    }
    if (tid < K_) {
        float c = 0.f;
#pragma unroll
        for (int w = 0; w < NWAVE; ++w) c += s_cnt[w * K_ + tid];
        out[K_ * D_ + tid] = c;
    }
}

// ---------------------------------------------------------------------------
// Stage 2a: two-level reduction, level 1. Grid = B_ * nch blocks; block
// (b, ch) sums rpc (=blk_per_b/nch) records into part2[b*nch+ch]. Thread t
// owns quads {t, t+256, (t<16: t+512)} in NAMED registers; per-thread loads
// ~= 3*rpc (short chains, high block-level parallelism — fixes r8's
// 8-blocks-only MLP bottleneck).
// ---------------------------------------------------------------------------
__global__ __launch_bounds__(TPB) void seg_reduce_a(
    const float* __restrict__ partials, float* __restrict__ part2,
    int rpc, int nch)
{
    const int blk = blockIdx.x;
    const int b   = blk / nch;
    const int ch  = blk - b * nch;
    const int tid = threadIdx.x;

    const float4* __restrict__ p4 = reinterpret_cast<const float4*>(partials)
        + (size_t)((b * nch + ch) * rpc) * RECQ;
    float4* __restrict__ o4 = reinterpret_cast<float4*>(part2)
        + (size_t)blk * RECQ;

    float4 acc0 = make_float4(0.f, 0.f, 0.f, 0.f);
    float4 acc1 = acc0, acc2 = acc0;
#pragma unroll 4
    for (int r = 0; r < rpc; ++r) {
        const float4* rp = p4 + (size_t)r * RECQ;
        float4 v0 = rp[tid];
        float4 v1 = rp[tid + 256];
        acc0.x += v0.x; acc0.y += v0.y; acc0.z += v0.z; acc0.w += v0.w;
        acc1.x += v1.x; acc1.y += v1.y; acc1.z += v1.z; acc1.w += v1.w;
        if (tid < 16) {
            float4 v2 = rp[tid + 512];
            acc2.x += v2.x; acc2.y += v2.y; acc2.z += v2.z; acc2.w += v2.w;
        }
    }
    o4[tid]       = acc0;
    o4[tid + 256] = acc1;
    if (tid < 16) o4[tid + 512] = acc2;
}

// ---------------------------------------------------------------------------
// Stage 2b+3: one block per batch. Prologue sums the batch's nch chunk
// partials (only nch loads per owned quad), then the r8-proven scatter to
// transposed s_cent4[j][k], normalize, pair loss, write batch_loss[b].
// ---------------------------------------------------------------------------
__global__ __launch_bounds__(TPB) void loss8_kernel(
    const float* __restrict__ part2, float* __restrict__ batch_loss,
    int nch)
{
    __shared__ __align__(16) float4 s_cent4[8 * K_];  // [j][k]
    __shared__ float s_cntsh[K_];
    __shared__ float s_pres[K_];
    __shared__ float s_wred[NWAVE];

    const int b   = blockIdx.x;
    const int tid = threadIdx.x;
    const float4* __restrict__ p4 = reinterpret_cast<const float4*>(part2)
        + (size_t)(b * nch) * RECQ;

    float4 acc0 = make_float4(0.f, 0.f, 0.f, 0.f);
    float4 acc1 = acc0, acc2 = acc0;
#pragma unroll 8
    for (int c = 0; c < nch; ++c) {
        const float4* rp = p4 + (size_t)c * RECQ;
        float4 v0 = rp[tid];
        float4 v1 = rp[tid + 256];
        acc0.x += v0.x; acc0.y += v0.y; acc0.z += v0.z; acc0.w += v0.w;
        acc1.x += v1.x; acc1.y += v1.y; acc1.z += v1.z; acc1.w += v1.w;
        if (tid < 16) {
            float4 v2 = rp[tid + 512];
            acc2.x += v2.x; acc2.y += v2.y; acc2.z += v2.z; acc2.w += v2.w;
        }
    }

    // scatter: quad q (<512) -> s_cent4[(q&7)*64 + (q>>3)]
    s_cent4[(tid & 7) * K_ + (tid >> 3)] = acc0;
    {
        const int q1 = tid + 256;
        s_cent4[(q1 & 7) * K_ + (q1 >> 3)] = acc1;
    }
    if (tid < 16) reinterpret_cast<float4*>(s_cntsh)[tid] = acc2;
    __syncthreads();

    if (tid < K_) s_pres[tid] = (s_cntsh[tid] > 0.5f) ? 1.f : 0.f;
    for (int i = tid; i < 8 * K_; i += TPB) {
        float inv = 1.0f / fmaxf(s_cntsh[i & 63], 1.0f);
        float4 c = s_cent4[i];
        c.x *= inv; c.y *= inv; c.z *= inv; c.w *= inv;
        s_cent4[i] = c;
    }
    __syncthreads();

    const int wave = tid >> 6, lane = tid & 63;

    float4 cb[8];
#pragma unroll
    for (int j = 0; j < 8; ++j) cb[j] = s_cent4[j * K_ + lane];
    const float pres2 = s_pres[lane];

    float acc = 0.f;
#pragma unroll 4
    for (int t = 0; t < 16; ++t) {
        const int k1 = wave * 16 + t;
        float dist = 0.f;
#pragma unroll
        for (int j = 0; j < 8; ++j) {
            float4 a = s_cent4[j * K_ + k1];   // wave-uniform broadcast
            dist += fabsf(a.x - cb[j].x) + fabsf(a.y - cb[j].y)
                  + fabsf(a.z - cb[j].z) + fabsf(a.w - cb[j].w);
        }
        float h = fmaxf(0.25f - dist, 0.f);
        float valid = (k1 < lane) ? s_pres[k1] * pres2 : 0.f;
        acc += valid * h * h;
    }
#pragma unroll
    for (int m = 32; m > 0; m >>= 1) acc += __shfl_xor(acc, m);
    if (lane == 0) s_wred[wave] = acc;
    __syncthreads();
    if (tid == 0) {
        float s = s_wred[0] + s_wred[1] + s_wred[2] + s_wred[3];
        float n = 0.f;
        for (int k = 0; k < K_; ++k) n += s_pres[k];
        float ncomp = n * (n - 1.f) * 0.5f;
        batch_loss[b] = (ncomp > 0.f) ? (s / ncomp) : 0.f;
    }
}

// ---------------------------------------------------------------------------
// Stage 4: average the 8 per-batch losses into out[0].
// ---------------------------------------------------------------------------
__global__ void final_kernel(const float* __restrict__ batch_loss,
                             float* __restrict__ out)
{
    if (threadIdx.x == 0) {
        float t = 0.f;
#pragma unroll
        for (int b = 0; b < B_; ++b) t += batch_loss[b];
        out[0] = t * (1.0f / (float)B_);
    }
}

// ---------------------------------------------------------------------------
extern "C" void kernel_launch(void* const* d_in, const int* in_sizes, int n_in,
                              void* d_out, int out_size, void* d_ws, size_t ws_size,
                              hipStream_t stream)
{
    const float* emb = (const float*)d_in[0];
    const int*   lab = (const int*)d_in[1];
    float*       out = (float*)d_out;
    float*       ws  = (float*)d_ws;

    int blk_per_b = 128;
    while (blk_per_b > 8) {
        size_t need = ((size_t)(blk_per_b * B_) * REC          // partials
                       + (size_t)(B_ * 8) * REC                // part2 (max)
                       + B_) * sizeof(float);
        if (need <= ws_size) break;
        blk_per_b >>= 1;
    }
    const int nblk = blk_per_b * B_;
    const int nch  = (blk_per_b >= 8) ? 8 : blk_per_b;
    const int rpc  = blk_per_b / nch;

    float* partials   = ws;
    float* part2      = ws + (size_t)nblk * REC;
    float* batch_loss = part2 + (size_t)(B_ * nch) * REC;

    seg_partial_kernel<<<nblk, TPB, 0, stream>>>(emb, lab, partials, blk_per_b);

    seg_reduce_a<<<B_ * nch, TPB, 0, stream>>>(partials, part2, rpc, nch);

    loss8_kernel<<<B_, TPB, 0, stream>>>(part2, batch_loss, nch);

    final_kernel<<<1, 64, 0, stream>>>(batch_loss, out);
}